// Round 3
// baseline (418.082 us; speedup 1.0000x reference)
//
#include <hip/hip_runtime.h>
#include <math.h>

#define S 4096
#define N_NODES 2048
#define N_CHILD 4096
#define NNZ 32768
#define NNZ_TOTAL (2 * NNZ)
#define TSM 512   // samples per main block (64 lanes x 8 fp8)
#define TN 16     // nodes per main block

typedef float f32x2 __attribute__((ext_vector_type(2)));

// shared memory overlay: texp tile OR csr scratch (different blocks of one kernel)
union SMem {
    unsigned short tile[64 * 130];                                  // 16640 B
    struct { int cnt[N_NODES]; int cur[N_NODES]; int ws[1024]; } csr; // 20480 B
};

// ---- prep: block 0 builds CSR; blocks 1..2048 do exp+transpose to fp8 ----
// ET layout: ET[(m*N_CHILD + c)*S + s] = fp8_e4m3(exp(ll_m[s, c]))

__global__ __launch_bounds__(1024) void prep_kernel(
        const float* __restrict__ ll0, const float* __restrict__ ll1,
        const float* __restrict__ w0d, const float* __restrict__ w1d,
        const int* __restrict__ w0r, const int* __restrict__ w0c,
        const int* __restrict__ w1r, const int* __restrict__ w1c,
        unsigned char* __restrict__ ET, int* __restrict__ ent_col,
        float* __restrict__ ent_ew, int* __restrict__ offsets) {
    __shared__ SMem sm;
    int t = threadIdx.x;
    if (blockIdx.x == 0) {
        // ---- CSR build, single block, LDS atomics ----
        for (int j = t; j < N_NODES; j += 1024) sm.csr.cnt[j] = 0;
        __syncthreads();
        for (int k = t; k < NNZ_TOTAL; k += 1024) {
            int row = (k < NNZ) ? w0r[k] : w1r[k - NNZ];
            atomicAdd(&sm.csr.cnt[row], 1);
        }
        __syncthreads();
        int c0 = sm.csr.cnt[2 * t], c1 = sm.csr.cnt[2 * t + 1];
        sm.csr.ws[t] = c0 + c1;
        __syncthreads();
        for (int off = 1; off < 1024; off <<= 1) {
            int v = (t >= off) ? sm.csr.ws[t - off] : 0;
            __syncthreads();
            sm.csr.ws[t] += v;
            __syncthreads();
        }
        int prefix = t ? sm.csr.ws[t - 1] : 0;
        sm.csr.cur[2 * t] = prefix;
        sm.csr.cur[2 * t + 1] = prefix + c0;
        offsets[2 * t] = prefix;
        offsets[2 * t + 1] = prefix + c0;
        if (t == 1023) offsets[N_NODES] = sm.csr.ws[1023];
        __syncthreads();
        for (int k = t; k < NNZ_TOTAL; k += 1024) {
            int row, col; float w;
            if (k < NNZ) { row = w0r[k]; col = w0c[k]; w = w0d[k]; }
            else { int kk = k - NNZ; row = w1r[kk]; col = w1c[kk] + N_CHILD; w = w1d[kk]; }
            int pos = atomicAdd(&sm.csr.cur[row], 1);
            ent_col[pos] = col;
            ent_ew[pos] = __expf(w);
        }
    } else {
        // ---- exp + transpose tile: 64 cols x 256 samples ----
        int b = blockIdx.x - 1;           // 0..2047
        int z = b >> 10;                  // matrix 0/1
        int rem = b & 1023;
        int ct = rem & 63, st = rem >> 6;
        int c0 = ct * 64, s0 = st * 256;
        const float* ll = z ? ll1 : ll0;
        int wave = t >> 6, lane = t & 63;
#pragma unroll
        for (int it = 0; it < 8; ++it) {
            int sh = it * 16 + wave;      // sample-pair index 0..127
            int s = s0 + sh * 2;
            float f0 = __expf(ll[(size_t)s * N_CHILD + c0 + lane]);        // 256 B/wave
            float f1 = __expf(ll[(size_t)(s + 1) * N_CHILD + c0 + lane]);
            unsigned int packed =
                (unsigned int)__builtin_amdgcn_cvt_pk_fp8_f32(f0, f1, 0, false);
            sm.tile[lane * 130 + sh] = (unsigned short)packed;  // bank (lane+sh/2)%32: 2-way, free
        }
        __syncthreads();
        unsigned char* dst = ET + (size_t)(z * N_CHILD + c0) * S + s0;
#pragma unroll
        for (int it = 0; it < 4; ++it) {
            int c = it * 16 + wave;
            unsigned int v = *(const unsigned int*)&sm.tile[c * 130 + lane * 2];
            *(unsigned int*)(dst + (size_t)c * S + lane * 4) = v;  // 256 B/wave contiguous
        }
    }
}

// ---- main: out[s,i] = log(sum_k ET[col_k, s] * ew_k) - log(sum_k ew_k) ----

static __device__ inline void fma8(uint2 x, float w, float* a) {
    f32x2 p0 = __builtin_amdgcn_cvt_pk_f32_fp8(x.x, false);
    f32x2 p1 = __builtin_amdgcn_cvt_pk_f32_fp8(x.x, true);
    f32x2 p2 = __builtin_amdgcn_cvt_pk_f32_fp8(x.y, false);
    f32x2 p3 = __builtin_amdgcn_cvt_pk_f32_fp8(x.y, true);
    a[0] = fmaf(p0.x, w, a[0]); a[1] = fmaf(p0.y, w, a[1]);
    a[2] = fmaf(p1.x, w, a[2]); a[3] = fmaf(p1.y, w, a[3]);
    a[4] = fmaf(p2.x, w, a[4]); a[5] = fmaf(p2.y, w, a[5]);
    a[6] = fmaf(p3.x, w, a[6]); a[7] = fmaf(p3.y, w, a[7]);
}

__global__ __launch_bounds__(256) void main_kernel(
        const unsigned char* __restrict__ ET, const int* __restrict__ ent_col,
        const float* __restrict__ ent_ew, const int* __restrict__ offsets,
        float* __restrict__ out) {
    __shared__ float lds[TSM * 17];   // [sample][node], node dim padded 16->17
    int t = threadIdx.x, wave = t >> 6, lane = t & 63;
    int slice = blockIdx.x & 7;       // XCD pin: 4 MB ET slice per XCD L2
    int nb = blockIdx.x >> 3;
    int i0 = nb * TN;
    const unsigned char* ETs = ET + slice * TSM + lane * 8;
    for (int jj = 0; jj < 4; ++jj) {
        int j = (wave << 2) + jj;     // each wave owns 4 nodes
        int i = i0 + j;
        int b = __builtin_amdgcn_readfirstlane(offsets[i]);
        int e = __builtin_amdgcn_readfirstlane(offsets[i + 1]);
        float a[8];
#pragma unroll
        for (int u = 0; u < 8; ++u) a[u] = 0.f;
        float z = 0.f;
        int k = b;
        for (; k + 1 < e; k += 2) {
            int cA = __builtin_amdgcn_readfirstlane(ent_col[k]);
            int cB = __builtin_amdgcn_readfirstlane(ent_col[k + 1]);
            float wA = ent_ew[k];
            float wB = ent_ew[k + 1];
            uint2 x = *(const uint2*)(ETs + (size_t)cA * S);   // 8 B/lane, 512 B/wave
            uint2 y = *(const uint2*)(ETs + (size_t)cB * S);
            fma8(x, wA, a);
            fma8(y, wB, a);
            z += wA + wB;
        }
        if (k < e) {
            int cA = __builtin_amdgcn_readfirstlane(ent_col[k]);
            float wA = ent_ew[k];
            uint2 x = *(const uint2*)(ETs + (size_t)cA * S);
            fma8(x, wA, a);
            z += wA;
        }
        float lz = __logf(z);
#pragma unroll
        for (int u = 0; u < 8; ++u)
            lds[(lane * 8 + u) * 17 + j] = __logf(a[u]) - lz;
    }
    __syncthreads();
    float* orow = out + (size_t)slice * TSM * N_NODES + i0;
#pragma unroll
    for (int q = 0; q < 32; ++q) {
        int p = t + 256 * q;
        int s_l = p >> 4;
        int i_l = p & (TN - 1);
        orow[(size_t)s_l * N_NODES + i_l] = lds[s_l * 17 + i_l];  // 64 B segments
    }
}

// ---- launch ---------------------------------------------------------------

extern "C" void kernel_launch(void* const* d_in, const int* in_sizes, int n_in,
                              void* d_out, int out_size, void* d_ws, size_t ws_size,
                              hipStream_t stream) {
    const float* ll0 = (const float*)d_in[0];
    const float* ll1 = (const float*)d_in[1];
    const float* w0d = (const float*)d_in[2];
    const float* w1d = (const float*)d_in[3];
    const int*   w0r = (const int*)d_in[4];
    const int*   w0c = (const int*)d_in[5];
    const int*   w1r = (const int*)d_in[6];
    const int*   w1c = (const int*)d_in[7];
    float* out = (float*)d_out;

    // workspace layout
    unsigned char* ET = (unsigned char*)d_ws;                    // 2*N_CHILD*S fp8 = 32 MiB
    int*   ent_col = (int*)(ET + (size_t)2 * N_CHILD * S);       // 65536 ints
    float* ent_ew  = (float*)(ent_col + NNZ_TOTAL);              // 65536 floats
    int*   offsets = (int*)(ent_ew + NNZ_TOTAL);                 // 2049 ints

    prep_kernel<<<2049, 1024, 0, stream>>>(ll0, ll1, w0d, w1d, w0r, w0c, w1r, w1c,
                                           ET, ent_col, ent_ew, offsets);
    main_kernel<<<(N_NODES / TN) * (S / TSM), 256, 0, stream>>>(ET, ent_col, ent_ew,
                                                                offsets, out);
}

// Round 4
// 224.904 us; speedup vs baseline: 1.8589x; 1.8589x over previous
//
#include <hip/hip_runtime.h>
#include <math.h>

#define S 4096
#define N_NODES 2048
#define N_CHILD 4096
#define NNZ 32768
#define NNZ_TOTAL (2 * NNZ)
#define TSM 512   // samples per main block (64 lanes x 8 fp8)
#define TN 16     // nodes per main block

typedef float f32x2 __attribute__((ext_vector_type(2)));

// ---- A: exp+transpose to fp8, with distributed histogram fused in ----------
// block bits: [0:2]=slice3 (sample-slice/XCD), [3]=sthalf, [4:9]=ct, [10]=z
// so the block writing ET samples [slice3*512, +512) sits on XCD slice3 (if %8
// dispatch holds) — same XCD that main_kernel reads that slice from.

__global__ __launch_bounds__(1024) void texp_hist_kernel(
        const float* __restrict__ ll0, const float* __restrict__ ll1,
        const int* __restrict__ w0r, const int* __restrict__ w1r,
        unsigned char* __restrict__ ET, int* __restrict__ counts) {
    __shared__ unsigned short tile[64 * 130];   // 16640 B
    int t = threadIdx.x;
    int b = blockIdx.x;
    if (t < 32) {   // fused hist: 32 entries per block, global atomics
        int k = b * 32 + t;
        int row = (k < NNZ) ? w0r[k] : w1r[k - NNZ];
        atomicAdd(&counts[row], 1);
    }
    int slice3 = b & 7;
    int sthalf = (b >> 3) & 1;
    int ct = (b >> 4) & 63;
    int z = (b >> 10) & 1;
    int c0 = ct * 64;
    int s0 = slice3 * 512 + sthalf * 256;
    const float* ll = z ? ll1 : ll0;
    int wave = t >> 6, lane = t & 63;
#pragma unroll
    for (int it = 0; it < 8; ++it) {
        int sh = it * 16 + wave;          // sample-pair 0..127
        int s = s0 + sh * 2;
        float f0 = __expf(ll[(size_t)s * N_CHILD + c0 + lane]);        // 256 B/wave
        float f1 = __expf(ll[(size_t)(s + 1) * N_CHILD + c0 + lane]);
        unsigned int packed =
            (unsigned int)__builtin_amdgcn_cvt_pk_fp8_f32(f0, f1, 0, false);
        tile[lane * 130 + sh] = (unsigned short)packed;   // bank lane%32: 2-way, free
    }
    __syncthreads();
    unsigned char* dst = ET + (size_t)(z * N_CHILD + c0) * S + s0;
#pragma unroll
    for (int it = 0; it < 4; ++it) {
        int c = it * 16 + wave;
        unsigned int v = *(const unsigned int*)&tile[c * 130 + lane * 2];
        *(unsigned int*)(dst + (size_t)c * S + lane * 4) = v;   // 256 B/wave contiguous
    }
}

// ---- B: scan counts -> offsets + cursor (pure LDS, ~3 us) ------------------

__global__ __launch_bounds__(1024) void scan_kernel(const int* __restrict__ counts,
                                                    int* __restrict__ offsets,
                                                    int* __restrict__ cursor) {
    __shared__ int ws[1024];
    int t = threadIdx.x;
    int c0 = counts[2 * t], c1 = counts[2 * t + 1];
    ws[t] = c0 + c1;
    __syncthreads();
    for (int off = 1; off < 1024; off <<= 1) {
        int v = (t >= off) ? ws[t - off] : 0;
        __syncthreads();
        ws[t] += v;
        __syncthreads();
    }
    int prefix = t ? ws[t - 1] : 0;
    offsets[2 * t] = prefix;
    offsets[2 * t + 1] = prefix + c0;
    cursor[2 * t] = prefix;
    cursor[2 * t + 1] = prefix + c0;
    if (t == 1023) offsets[N_NODES] = ws[1023];
}

// ---- C: parallel scatter with global cursor atomics ------------------------

__global__ __launch_bounds__(1024) void scatter_kernel(
        const int* __restrict__ w0r, const int* __restrict__ w0c,
        const float* __restrict__ w0d,
        const int* __restrict__ w1r, const int* __restrict__ w1c,
        const float* __restrict__ w1d,
        int* __restrict__ cursor, int* __restrict__ ent_col,
        float* __restrict__ ent_ew) {
    int k = blockIdx.x * 1024 + threadIdx.x;
    int row, col; float w;
    if (k < NNZ) { row = w0r[k]; col = w0c[k]; w = w0d[k]; }
    else { int kk = k - NNZ; row = w1r[kk]; col = w1c[kk] + N_CHILD; w = w1d[kk]; }
    int pos = atomicAdd(&cursor[row], 1);
    ent_col[pos] = col;
    ent_ew[pos] = __expf(w);
}

// ---- D: main: out[s,i] = log(sum_k ET[col_k,s]*ew_k) - log(sum_k ew_k) -----

static __device__ inline void fma8(uint2 x, float w, float* a) {
    f32x2 p0 = __builtin_amdgcn_cvt_pk_f32_fp8(x.x, false);
    f32x2 p1 = __builtin_amdgcn_cvt_pk_f32_fp8(x.x, true);
    f32x2 p2 = __builtin_amdgcn_cvt_pk_f32_fp8(x.y, false);
    f32x2 p3 = __builtin_amdgcn_cvt_pk_f32_fp8(x.y, true);
    a[0] = fmaf(p0.x, w, a[0]); a[1] = fmaf(p0.y, w, a[1]);
    a[2] = fmaf(p1.x, w, a[2]); a[3] = fmaf(p1.y, w, a[3]);
    a[4] = fmaf(p2.x, w, a[4]); a[5] = fmaf(p2.y, w, a[5]);
    a[6] = fmaf(p3.x, w, a[6]); a[7] = fmaf(p3.y, w, a[7]);
}

__global__ __launch_bounds__(256) void main_kernel(
        const unsigned char* __restrict__ ET, const int* __restrict__ ent_col,
        const float* __restrict__ ent_ew, const int* __restrict__ offsets,
        float* __restrict__ out) {
    __shared__ float lds[TSM * 17];
    int t = threadIdx.x, wave = t >> 6, lane = t & 63;
    int slice = blockIdx.x & 7;       // XCD pin: 4 MB fp8 ET slice per XCD L2
    int nb = blockIdx.x >> 3;
    int i0 = nb * TN;
    const unsigned char* ETs = ET + slice * TSM + lane * 8;
    for (int jj = 0; jj < 4; ++jj) {
        int j = (wave << 2) + jj;
        int i = i0 + j;
        int b = __builtin_amdgcn_readfirstlane(offsets[i]);
        int e = __builtin_amdgcn_readfirstlane(offsets[i + 1]);
        float a[8];
#pragma unroll
        for (int u = 0; u < 8; ++u) a[u] = 0.f;
        float z = 0.f;
        int k = b;
        for (; k + 3 < e; k += 4) {   // 4 independent 8B loads = 2KB/wave in flight
            int cA = __builtin_amdgcn_readfirstlane(ent_col[k]);
            int cB = __builtin_amdgcn_readfirstlane(ent_col[k + 1]);
            int cC = __builtin_amdgcn_readfirstlane(ent_col[k + 2]);
            int cD = __builtin_amdgcn_readfirstlane(ent_col[k + 3]);
            float wA = ent_ew[k], wB = ent_ew[k + 1];
            float wC = ent_ew[k + 2], wD = ent_ew[k + 3];
            uint2 xA = *(const uint2*)(ETs + (size_t)cA * S);
            uint2 xB = *(const uint2*)(ETs + (size_t)cB * S);
            uint2 xC = *(const uint2*)(ETs + (size_t)cC * S);
            uint2 xD = *(const uint2*)(ETs + (size_t)cD * S);
            fma8(xA, wA, a); fma8(xB, wB, a); fma8(xC, wC, a); fma8(xD, wD, a);
            z += wA + wB + wC + wD;
        }
        for (; k < e; ++k) {
            int cA = __builtin_amdgcn_readfirstlane(ent_col[k]);
            float wA = ent_ew[k];
            uint2 xA = *(const uint2*)(ETs + (size_t)cA * S);
            fma8(xA, wA, a);
            z += wA;
        }
        float lz = __logf(z);
#pragma unroll
        for (int u = 0; u < 8; ++u)
            lds[(lane * 8 + u) * 17 + j] = __logf(a[u]) - lz;
    }
    __syncthreads();
    float* orow = out + (size_t)slice * TSM * N_NODES + i0;
#pragma unroll
    for (int q = 0; q < 32; ++q) {
        int p = t + 256 * q;
        int s_l = p >> 4;
        int i_l = p & (TN - 1);
        // NT store: don't let the 32MB out stream evict the ET slice from L2
        __builtin_nontemporal_store(lds[s_l * 17 + i_l],
                                    &orow[(size_t)s_l * N_NODES + i_l]);
    }
}

// ---- launch ---------------------------------------------------------------

extern "C" void kernel_launch(void* const* d_in, const int* in_sizes, int n_in,
                              void* d_out, int out_size, void* d_ws, size_t ws_size,
                              hipStream_t stream) {
    const float* ll0 = (const float*)d_in[0];
    const float* ll1 = (const float*)d_in[1];
    const float* w0d = (const float*)d_in[2];
    const float* w1d = (const float*)d_in[3];
    const int*   w0r = (const int*)d_in[4];
    const int*   w0c = (const int*)d_in[5];
    const int*   w1r = (const int*)d_in[6];
    const int*   w1c = (const int*)d_in[7];
    float* out = (float*)d_out;

    unsigned char* ET = (unsigned char*)d_ws;                    // 32 MiB
    int*   ent_col = (int*)(ET + (size_t)2 * N_CHILD * S);       // 65536
    float* ent_ew  = (float*)(ent_col + NNZ_TOTAL);              // 65536
    int*   counts  = (int*)(ent_ew + NNZ_TOTAL);                 // 2048
    int*   offsets = counts + N_NODES;                           // 2049
    int*   cursor  = offsets + N_NODES + 1;                      // 2048

    hipMemsetAsync(counts, 0, sizeof(int) * N_NODES, stream);
    texp_hist_kernel<<<2048, 1024, 0, stream>>>(ll0, ll1, w0r, w1r, ET, counts);
    scan_kernel<<<1, 1024, 0, stream>>>(counts, offsets, cursor);
    scatter_kernel<<<NNZ_TOTAL / 1024, 1024, 0, stream>>>(w0r, w0c, w0d, w1r, w1c, w1d,
                                                          cursor, ent_col, ent_ew);
    main_kernel<<<(N_NODES / TN) * (S / TSM), 256, 0, stream>>>(ET, ent_col, ent_ew,
                                                                offsets, out);
}

// Round 5
// 222.022 us; speedup vs baseline: 1.8831x; 1.0130x over previous
//
#include <hip/hip_runtime.h>
#include <math.h>

#define S 4096
#define N_NODES 2048
#define N_CHILD 4096
#define NNZ 32768
#define NNZ_TOTAL (2 * NNZ)
#define TSM 512    // samples per main block
#define TN 8       // nodes per main block
#define CAP 96     // padded-row capacity (mean 32, sigma 5.7 -> 96 is +11 sigma)
#define LP 516     // lds row pitch (floats) in main

typedef float f32x2 __attribute__((ext_vector_type(2)));

// ---- prep: blocks 0..63 scatter entries to padded rows; 64..2111 exp+transpose
// ET layout: ET[(m*N_CHILD + c)*S + s] = fp8_e4m3(exp(ll_m[s, c]))
// texp block bits (bt = b-64): [0:2]=slice (XCD pin), [3]=sthalf, [4:9]=ct, [10]=z

__global__ __launch_bounds__(1024, 8) void prep_kernel(
        const float* __restrict__ ll0, const float* __restrict__ ll1,
        const float* __restrict__ w0d, const float* __restrict__ w1d,
        const int* __restrict__ w0r, const int* __restrict__ w0c,
        const int* __restrict__ w1r, const int* __restrict__ w1c,
        unsigned char* __restrict__ ET, int2* __restrict__ ent,
        int* __restrict__ counts) {
    __shared__ unsigned short tile[64 * 130];   // 16640 B
    int t = threadIdx.x;
    int b = blockIdx.x;
    if (b < 64) {
        // ---- scatter: fully parallel, no scan needed (padded rows) ----
        int k = b * 1024 + t;
        int row, col; float w;
        if (k < NNZ) { row = w0r[k]; col = w0c[k]; w = w0d[k]; }
        else { int kk = k - NNZ; row = w1r[kk]; col = w1c[kk] + N_CHILD; w = w1d[kk]; }
        int pos = atomicAdd(&counts[row], 1);
        if (pos < CAP)
            ent[row * CAP + pos] = make_int2(col, __float_as_int(__expf(w)));
        return;
    }
    // ---- exp + transpose tile: 64 cols x 256 samples ----
    int bt = b - 64;
    int slice = bt & 7;
    int sthalf = (bt >> 3) & 1;
    int ct = (bt >> 4) & 63;
    int z = (bt >> 10) & 1;
    int c0 = ct * 64;
    int s0 = slice * 512 + sthalf * 256;
    const float* ll = z ? ll1 : ll0;
    int wave = t >> 6, lane = t & 63;
    // preload ALL 16 values -> 16 loads in flight per wave (VGPR-backed)
    float v0[8], v1[8];
    const float* p = ll + (size_t)(s0 + wave * 2) * N_CHILD + c0 + lane;
#pragma unroll
    for (int it = 0; it < 8; ++it) {
        v0[it] = p[0];
        v1[it] = p[N_CHILD];
        p += 32 * (size_t)N_CHILD;
    }
#pragma unroll
    for (int it = 0; it < 8; ++it) {
        int sh = it * 16 + wave;          // sample-pair 0..127
        unsigned int packed = (unsigned int)__builtin_amdgcn_cvt_pk_fp8_f32(
            __expf(v0[it]), __expf(v1[it]), 0, false);
        tile[lane * 130 + sh] = (unsigned short)packed;   // 2-way bank alias: free
    }
    __syncthreads();
    unsigned char* dst = ET + (size_t)(z * N_CHILD + c0) * S + s0;
#pragma unroll
    for (int it = 0; it < 4; ++it) {
        int c = it * 16 + wave;
        unsigned int v = *(const unsigned int*)&tile[c * 130 + lane * 2];
        *(unsigned int*)(dst + (size_t)c * S + lane * 4) = v;   // 256 B/wave contiguous
    }
}

// ---- main: out[s,i] = log(sum_k ET[col_k,s]*ew_k) - log(sum_k ew_k) --------

static __device__ inline void fma16(uint4 x, float w, float* a) {
#pragma unroll
    for (int q = 0; q < 4; ++q) {
        unsigned int word = (q == 0) ? x.x : (q == 1) ? x.y : (q == 2) ? x.z : x.w;
        f32x2 lo = __builtin_amdgcn_cvt_pk_f32_fp8(word, false);
        f32x2 hi = __builtin_amdgcn_cvt_pk_f32_fp8(word, true);
        a[q * 4 + 0] = fmaf(lo.x, w, a[q * 4 + 0]);
        a[q * 4 + 1] = fmaf(lo.y, w, a[q * 4 + 1]);
        a[q * 4 + 2] = fmaf(hi.x, w, a[q * 4 + 2]);
        a[q * 4 + 3] = fmaf(hi.y, w, a[q * 4 + 3]);
    }
}

__global__ __launch_bounds__(256, 8) void main_kernel(
        const unsigned char* __restrict__ ET, const int2* __restrict__ ent,
        const int* __restrict__ counts, float* __restrict__ out) {
    __shared__ float lds[TN * LP];    // [node][sample] 16512 B
    int t = threadIdx.x, wave = t >> 6, lane = t & 63;
    int hs = lane >> 5, sl = lane & 31;   // half-wave: hs=0 even entries, hs=1 odd
    int slice = blockIdx.x & 7;           // XCD pin: 4 MB fp8 ET slice per XCD L2
    int nb = blockIdx.x >> 3;
    int i0 = nb * TN;
    const unsigned char* ETs = ET + slice * TSM + sl * 16;   // lane covers 16 samples
    for (int jj = 0; jj < 2; ++jj) {
        int j = wave * 2 + jj;            // each wave owns 2 nodes
        int i = i0 + j;
        int cnt = __builtin_amdgcn_readfirstlane(counts[i]);
        if (cnt > CAP) cnt = CAP;
        const int2* eb = ent + i * CAP;
        float a[16];
#pragma unroll
        for (int u = 0; u < 16; ++u) a[u] = 0.f;
        float z = 0.f;
        int n = (cnt + 1 - hs) >> 1;      // entries for this half: hs, hs+2, ...
        int t2 = 0;
        for (; t2 + 1 < n; t2 += 2) {     // 2 x 16B loads in flight per lane
            int2 e0 = eb[hs + 2 * t2];
            int2 e1 = eb[hs + 2 * t2 + 2];
            uint4 x0 = *(const uint4*)(ETs + (size_t)e0.x * S);
            uint4 x1 = *(const uint4*)(ETs + (size_t)e1.x * S);
            float w0 = __uint_as_float(e0.y);
            float w1 = __uint_as_float(e1.y);
            fma16(x0, w0, a);
            fma16(x1, w1, a);
            z += w0 + w1;
        }
        if (t2 < n) {
            int2 e0 = eb[hs + 2 * t2];
            uint4 x0 = *(const uint4*)(ETs + (size_t)e0.x * S);
            float w0 = __uint_as_float(e0.y);
            fma16(x0, w0, a);
            z += w0;
        }
        // cross-half reduction: lanes l and l^32 hold partials of same outputs
#pragma unroll
        for (int u = 0; u < 16; ++u) a[u] += __shfl_xor(a[u], 32);
        z += __shfl_xor(z, 32);
        float lz = __logf(z);
        // halves split the log work: hs=0 stores u=0..7, hs=1 stores u=8..15
        float r[8];
#pragma unroll
        for (int u = 0; u < 8; ++u) r[u] = __logf(a[hs * 8 + u]) - lz;
        float* dstl = &lds[j * LP + sl * 16 + hs * 8];
        *(float4*)(dstl)     = make_float4(r[0], r[1], r[2], r[3]);
        *(float4*)(dstl + 4) = make_float4(r[4], r[5], r[6], r[7]);
    }
    __syncthreads();
    // out write: 512 samples x 8 nodes, float2/lane -> 512 B contiguous per wave
    float* obase = out + (size_t)slice * TSM * N_NODES + i0;
#pragma unroll
    for (int q = 0; q < 8; ++q) {
        int elem = (t + 256 * q) * 2;     // 0..4094, even
        int s_l = elem >> 3;
        int i_l = elem & 7;               // 0,2,4,6
        float2 v;
        v.x = lds[i_l * LP + s_l];
        v.y = lds[(i_l + 1) * LP + s_l];
        *(float2*)&obase[(size_t)s_l * N_NODES + i_l] = v;
    }
}

// ---- launch ---------------------------------------------------------------

extern "C" void kernel_launch(void* const* d_in, const int* in_sizes, int n_in,
                              void* d_out, int out_size, void* d_ws, size_t ws_size,
                              hipStream_t stream) {
    const float* ll0 = (const float*)d_in[0];
    const float* ll1 = (const float*)d_in[1];
    const float* w0d = (const float*)d_in[2];
    const float* w1d = (const float*)d_in[3];
    const int*   w0r = (const int*)d_in[4];
    const int*   w0c = (const int*)d_in[5];
    const int*   w1r = (const int*)d_in[6];
    const int*   w1c = (const int*)d_in[7];
    float* out = (float*)d_out;

    unsigned char* ET = (unsigned char*)d_ws;                    // 32 MiB
    int2* ent   = (int2*)(ET + (size_t)2 * N_CHILD * S);         // 2048*96*8 B
    int*  counts = (int*)(ent + (size_t)N_NODES * CAP);          // 2048

    hipMemsetAsync(counts, 0, sizeof(int) * N_NODES, stream);
    prep_kernel<<<2112, 1024, 0, stream>>>(ll0, ll1, w0d, w1d, w0r, w0c, w1r, w1c,
                                           ET, ent, counts);
    main_kernel<<<(N_NODES / TN) * (S / TSM), 256, 0, stream>>>(ET, ent, counts, out);
}